// Round 6
// baseline (332.511 us; speedup 1.0000x reference)
//
#include <hip/hip_runtime.h>
#include <hip/hip_bf16.h>

#define N_NODES 50000
#define N_EDGES 800000
#define IN_CH 256
#define OUT_CH 64
#define NEG_BIG -9e15f
#define NBLK_E 3125   // N_EDGES / 256

typedef __bf16 bfvec8 __attribute__((ext_vector_type(8)));
typedef float floatx4 __attribute__((ext_vector_type(4)));

// ---- ws layout (bytes), total ~15.5 MB ----
#define WS_WHB   0          // bf16 [50000][64]   6,400,000
#define WS_W32   6400000    // fp32 [800000]      3,200,000  sorted exp weights
#define WS_PSRC  9600000    // u16  [800000]      1,600,000  sorted src
#define WS_SRC16 11200000   // u16  [800000]      1,600,000
#define WS_DST16 12800000   // u16  [800000]      1,600,000
#define WS_CNT   14400000   // int  [50000]
#define WS_ROWP  14600000   // int  [50000]
#define WS_WOFS  14800000   // int  [50000]
#define WS_WTH   15000000   // bf16 [64][256]        32,768
#define WS_WTL   15040000   // bf16 [64][256]        32,768
#define WS_ESRC  15080000   // fp32 [50000]
#define WS_EDST  15280000   // fp32 [50000]
#define WS_BMAX  15480000   // fp32 [3125]
#define WS_BSUM  15496000   // fp32 [3125]
#define WS_M     15512000
#define WS_Z     15512004
#define WS_FLAGS 15512008   // int[2]: {edge_is_i64, float_is_f32}

// ---------- dtype-flexible helpers ----------
__device__ __forceinline__ float loadf(const void* p, size_t i, int isf32) {
    return isf32 ? ((const float*)p)[i]
                 : __bfloat162float(((const __hip_bfloat16*)p)[i]);
}
__device__ __forceinline__ void load_edge(const int* __restrict__ ei, int i, int f64,
                                          int& s, int& d) {
    if (f64) { s = ei[2 * i]; d = ei[2 * (N_EDGES + i)]; }
    else     { s = ei[i];     d = ei[N_EDGES + i]; }
    s = min(max(s, 0), N_NODES - 1);
    d = min(max(d, 0), N_NODES - 1);
}

// ---------- K0: detect edge int64 and float fp32 ----------
__global__ __launch_bounds__(256) void k_flags(const int* __restrict__ ei,
                                               const unsigned* __restrict__ xw,
                                               int* __restrict__ flags) {
    int t = threadIdx.x;
    int v = 0;
    for (int i = t; i < 2048; i += 256) v |= ei[2 * i + 1];
    unsigned lo = xw[t] & 0xFFFFu;
    unsigned e8 = (lo >> 7) & 0xFFu;
    int hit = (e8 >= 96u && e8 <= 144u) ? 1 : 0;
#pragma unroll
    for (int off = 32; off > 0; off >>= 1) {
        v |= __shfl_down(v, off);
        hit += __shfl_down(hit, off);
    }
    __shared__ int sv[4], sh[4];
    if ((t & 63) == 0) { sv[t >> 6] = v; sh[t >> 6] = hit; }
    __syncthreads();
    if (t == 0) {
        flags[0] = ((sv[0] | sv[1] | sv[2] | sv[3]) == 0) ? 1 : 0;
        flags[1] = ((sh[0] + sh[1] + sh[2] + sh[3]) < 192) ? 1 : 0;
    }
}

// ---------- K1: Wt hi/lo split-transpose ----------
__global__ __launch_bounds__(256) void k_prep(const void* __restrict__ Wv,
                                              const int* __restrict__ flags,
                                              __bf16* __restrict__ Wth,
                                              __bf16* __restrict__ Wtl) {
    int isf = flags[1];
    int t = blockIdx.x * 256 + threadIdx.x;   // 0..16383
    int c = t >> 8, k = t & 255;
    float w = loadf(Wv, (size_t)k * OUT_CH + c, isf);
    __bf16 h = (__bf16)w;
    Wth[t] = h;
    Wtl[t] = (__bf16)(w - (float)h);
}

// ---------- K2: wh = x @ W via split-bf16 MFMA + fused fp32 logits ----------
__global__ __launch_bounds__(256) void k_mm(const void* __restrict__ xv,
                                            const __bf16* __restrict__ Wth,
                                            const __bf16* __restrict__ Wtl,
                                            const void* __restrict__ av,
                                            const int* __restrict__ flags,
                                            __bf16* __restrict__ whb,
                                            float* __restrict__ esrc,
                                            float* __restrict__ edst) {
    int isf = flags[1];
    int gw = (blockIdx.x * 256 + (int)threadIdx.x) >> 6;
    if (gw >= N_NODES / 16) return;           // wave-uniform
    int lane = threadIdx.x & 63;
    int m = lane & 15, quad = lane >> 4;
    int nb = gw * 16;

    floatx4 acc[4];
#pragma unroll
    for (int ct = 0; ct < 4; ++ct) acc[ct] = (floatx4){0.f, 0.f, 0.f, 0.f};

#pragma unroll
    for (int s = 0; s < 8; ++s) {
        int k0 = s * 32 + quad * 8;
        bfvec8 ahi, alo;
        if (isf) {
            const float* xr = (const float*)xv + (size_t)(nb + m) * IN_CH + k0;
            float v[8];
            *(floatx4*)(v)     = *(const floatx4*)(xr);
            *(floatx4*)(v + 4) = *(const floatx4*)(xr + 4);
#pragma unroll
            for (int j = 0; j < 8; ++j) {
                __bf16 h = (__bf16)v[j];
                ahi[j] = h;
                alo[j] = (__bf16)(v[j] - (float)h);
            }
        } else {
            ahi = *(const bfvec8*)((const __bf16*)xv + (size_t)(nb + m) * IN_CH + k0);
#pragma unroll
            for (int j = 0; j < 8; ++j) alo[j] = (__bf16)0.0f;
        }
#pragma unroll
        for (int ct = 0; ct < 4; ++ct) {
            bfvec8 bhi = *(const bfvec8*)(Wth + (ct * 16 + m) * IN_CH + k0);
            bfvec8 blo = *(const bfvec8*)(Wtl + (ct * 16 + m) * IN_CH + k0);
            acc[ct] = __builtin_amdgcn_mfma_f32_16x16x32_bf16(ahi, blo, acc[ct], 0, 0, 0);
            acc[ct] = __builtin_amdgcn_mfma_f32_16x16x32_bf16(alo, bhi, acc[ct], 0, 0, 0);
            acc[ct] = __builtin_amdgcn_mfma_f32_16x16x32_bf16(ahi, bhi, acc[ct], 0, 0, 0);
        }
    }

    float a1[4], a2[4];
#pragma unroll
    for (int ct = 0; ct < 4; ++ct) {
        a1[ct] = loadf(av, ct * 16 + m, isf);
        a2[ct] = loadf(av, OUT_CH + ct * 16 + m, isf);
    }
#pragma unroll
    for (int r = 0; r < 4; ++r) {
        int node = nb + quad * 4 + r;
        float s1 = 0.f, s2 = 0.f;
#pragma unroll
        for (int ct = 0; ct < 4; ++ct) {
            float vv = acc[ct][r];
            whb[(size_t)node * OUT_CH + ct * 16 + m] = (__bf16)vv;
            s1 += vv * a1[ct];
            s2 += vv * a2[ct];
        }
#pragma unroll
        for (int off = 1; off < 16; off <<= 1) {
            s1 += __shfl_xor(s1, off);
            s2 += __shfl_xor(s2, off);
        }
        if (m == 0) { esrc[node] = s1; edst[node] = s2; }
    }
}

// ---------- K3: u16 idx + filtered histogram + block max ----------
__global__ __launch_bounds__(256) void k_edge(const int* __restrict__ ei,
                                              const int* __restrict__ flags,
                                              const float* __restrict__ esrc,
                                              const float* __restrict__ edst,
                                              unsigned short* __restrict__ src16,
                                              unsigned short* __restrict__ dst16,
                                              int* __restrict__ cnt,
                                              float* __restrict__ bmax) {
    int f64 = flags[0];
    int i = blockIdx.x * 256 + threadIdx.x;
    int s, d;
    load_edge(ei, i, f64, s, d);
    src16[i] = (unsigned short)s;
    dst16[i] = (unsigned short)d;
    float v = esrc[s] + edst[d];
    float ev = v > 0.0f ? v : NEG_BIG;
    if (v > 0.0f) atomicAdd(&cnt[d], 1);
    float mx = ev;
#pragma unroll
    for (int off = 32; off > 0; off >>= 1) mx = fmaxf(mx, __shfl_down(mx, off));
    __shared__ float sm[4];
    if ((threadIdx.x & 63) == 0) sm[threadIdx.x >> 6] = mx;
    __syncthreads();
    if (threadIdx.x == 0)
        bmax[blockIdx.x] = fmaxf(fmaxf(sm[0], sm[1]), fmaxf(sm[2], sm[3]));
}

// ---------- K4: 3-phase single-block scan of cnt + bmax->M ----------
__global__ __launch_bounds__(1024) void k_scan(const int* __restrict__ cnt,
                                               int* __restrict__ rowptr,
                                               int* __restrict__ wofs,
                                               const float* __restrict__ bmax,
                                               float* __restrict__ M) {
    __shared__ int lws[16];
    __shared__ float smax[16];
    int tid = threadIdx.x, lane = tid & 63, wid = tid >> 6;

    // phase 0: M = max(bmax)
    float mx = NEG_BIG;
    for (int i = tid; i < NBLK_E; i += 1024) mx = fmaxf(mx, bmax[i]);
#pragma unroll
    for (int off = 32; off > 0; off >>= 1) mx = fmaxf(mx, __shfl_down(mx, off));
    if (lane == 0) smax[wid] = mx;

    // phase 1: blocked per-thread sums (thread t owns [49t, 49t+49))
    const int C = 49;
    int beg = tid * C;
    int end = min(beg + C, N_NODES);
    int sum = 0;
    for (int i = beg; i < end; ++i) sum += cnt[i];

    // phase 2: exclusive scan of the 1024 partial sums
    int incl = sum;
#pragma unroll
    for (int off = 1; off < 64; off <<= 1) {
        int t = __shfl_up(incl, off);
        if (lane >= off) incl += t;
    }
    if (lane == 63) lws[wid] = incl;
    __syncthreads();
    if (tid == 0) {
        float m2 = smax[0];
#pragma unroll
        for (int i = 1; i < 16; ++i) m2 = fmaxf(m2, smax[i]);
        *M = m2;
    }
    if (wid == 0) {
        int wv = (lane < 16) ? lws[lane] : 0;
        int wincl = wv;
#pragma unroll
        for (int off = 1; off < 16; off <<= 1) {
            int t = __shfl_up(wincl, off);
            if (lane >= off) wincl += t;
        }
        if (lane < 16) lws[lane] = wincl;
    }
    __syncthreads();
    int base = ((wid == 0) ? 0 : lws[wid - 1]) + (incl - sum);

    // phase 3: re-walk, write exclusive prefixes
    int run = base;
    for (int i = beg; i < end; ++i) {
        int v = cnt[i];
        rowptr[i] = run;
        wofs[i] = run;
        run += v;
    }
}

// ---------- K5: exp (recomputed scores) + block sum + CSR placement ----------
__global__ __launch_bounds__(256) void k_exp(const float* __restrict__ Mp,
                                             const float* __restrict__ esrc,
                                             const float* __restrict__ edst,
                                             const unsigned short* __restrict__ src16,
                                             const unsigned short* __restrict__ dst16,
                                             int* __restrict__ wofs,
                                             float* __restrict__ w32,
                                             unsigned short* __restrict__ psrc,
                                             float* __restrict__ bsum) {
    float M = *Mp;
    int i = blockIdx.x * 256 + threadIdx.x;
    int s = src16[i], d = dst16[i];
    float v = esrc[s] + edst[d];
    float ev = v > 0.0f ? v : NEG_BIG;
    float t = expf(ev - M);          // masked edges: exp(-9e15-M) == 0
    if (v > 0.0f) {
        int pos = atomicAdd(&wofs[d], 1);
        w32[pos] = t;
        psrc[pos] = (unsigned short)s;
    }
#pragma unroll
    for (int off = 32; off > 0; off >>= 1) t += __shfl_down(t, off);
    __shared__ float sm[4];
    if ((threadIdx.x & 63) == 0) sm[threadIdx.x >> 6] = t;
    __syncthreads();
    if (threadIdx.x == 0) bsum[blockIdx.x] = sm[0] + sm[1] + sm[2] + sm[3];
}

// ---------- K6: reduce block sums -> Z ----------
__global__ __launch_bounds__(256) void k_rsum(const float* __restrict__ bsum,
                                              float* __restrict__ Z) {
    float s = 0.0f;
    for (int i = threadIdx.x; i < NBLK_E; i += 256) s += bsum[i];
#pragma unroll
    for (int off = 32; off > 0; off >>= 1) s += __shfl_down(s, off);
    __shared__ float sm[4];
    if ((threadIdx.x & 63) == 0) sm[threadIdx.x >> 6] = s;
    __syncthreads();
    if (threadIdx.x == 0) *Z = sm[0] + sm[1] + sm[2] + sm[3];
}

// ---------- K7: CSR gather, wave per dst node, lane = channel; fused ELU ----------
__global__ __launch_bounds__(256) void k_gather(const int* __restrict__ rowptr,
                                                const int* __restrict__ wofs,
                                                const float* __restrict__ w32,
                                                const unsigned short* __restrict__ psrc,
                                                const __bf16* __restrict__ whb,
                                                const float* __restrict__ Zp,
                                                float* __restrict__ out) {
    int gw = (blockIdx.x * 256 + (int)threadIdx.x) >> 6;   // dst node
    int c = threadIdx.x & 63;
    int beg = rowptr[gw];
    int end = wofs[gw];
    float Z = *Zp;
    float invZ = (Z > 0.0f) ? 1.0f / Z : 0.0f;
    float acc = 0.0f;
    for (int j = beg; j < end; ++j) {
        float t = w32[j];
        int s = psrc[j];
        acc += t * (float)whb[(size_t)s * OUT_CH + c];
    }
    float h = acc * invZ;
    out[(size_t)gw * OUT_CH + c] = h > 0.0f ? h : expf(h) - 1.0f;
}

extern "C" void kernel_launch(void* const* d_in, const int* in_sizes, int n_in,
                              void* d_out, int out_size, void* d_ws, size_t ws_size,
                              hipStream_t stream) {
    const void* x  = d_in[0];
    const int* ei  = (const int*)d_in[1];
    const void* W  = d_in[2];
    const void* a  = d_in[3];
    float* out     = (float*)d_out;

    char* ws = (char*)d_ws;
    __bf16* whb  = (__bf16*)(ws + WS_WHB);
    float* w32   = (float*)(ws + WS_W32);
    unsigned short* psrc  = (unsigned short*)(ws + WS_PSRC);
    unsigned short* src16 = (unsigned short*)(ws + WS_SRC16);
    unsigned short* dst16 = (unsigned short*)(ws + WS_DST16);
    int* cnt     = (int*)(ws + WS_CNT);
    int* rowptr  = (int*)(ws + WS_ROWP);
    int* wofs    = (int*)(ws + WS_WOFS);
    __bf16* Wth  = (__bf16*)(ws + WS_WTH);
    __bf16* Wtl  = (__bf16*)(ws + WS_WTL);
    float* esrc  = (float*)(ws + WS_ESRC);
    float* edst  = (float*)(ws + WS_EDST);
    float* bmax  = (float*)(ws + WS_BMAX);
    float* bsum  = (float*)(ws + WS_BSUM);
    float* M     = (float*)(ws + WS_M);
    float* Z     = (float*)(ws + WS_Z);
    int*   flags = (int*)(ws + WS_FLAGS);

    hipMemsetAsync(cnt, 0, N_NODES * sizeof(int), stream);

    k_flags <<<1,    256, 0, stream>>>(ei, (const unsigned*)x, flags);
    k_prep  <<<64,   256, 0, stream>>>(W, flags, Wth, Wtl);
    k_mm    <<<782,  256, 0, stream>>>(x, Wth, Wtl, a, flags, whb, esrc, edst);
    k_edge  <<<NBLK_E, 256, 0, stream>>>(ei, flags, esrc, edst, src16, dst16, cnt, bmax);
    k_scan  <<<1,   1024, 0, stream>>>(cnt, rowptr, wofs, bmax, M);
    k_exp   <<<NBLK_E, 256, 0, stream>>>(M, esrc, edst, src16, dst16, wofs, w32, psrc, bsum);
    k_rsum  <<<1,    256, 0, stream>>>(bsum, Z);
    k_gather<<<N_NODES / 4, 256, 0, stream>>>(rowptr, wofs, w32, psrc, whb, Z, out);
}

// Round 7
// 236.378 us; speedup vs baseline: 1.4067x; 1.4067x over previous
//
#include <hip/hip_runtime.h>
#include <hip/hip_bf16.h>

#define N_NODES 50000
#define N_EDGES 800000
#define IN_CH 256
#define OUT_CH 64
#define NEG_BIG -9e15f
#define NBLK_E 3125   // N_EDGES / 256
#define NBLK_N 196    // ceil(50000/256)

typedef __bf16 bfvec8 __attribute__((ext_vector_type(8)));
typedef float floatx4 __attribute__((ext_vector_type(4)));

// ---- ws layout (bytes), total ~15.5 MB ----
#define WS_WHB   0          // bf16 [50000][64]   6,400,000
#define WS_W32   6400000    // fp32 [800000]      3,200,000  sorted exp weights
#define WS_PSRC  9600000    // u16  [800000]      1,600,000  sorted src
#define WS_SRC16 11200000   // u16  [800000]      1,600,000
#define WS_DST16 12800000   // u16  [800000]      1,600,000
#define WS_CNT   14400000   // int  [50000]
#define WS_ROWP  14600000   // int  [50000]
#define WS_WOFS  14800000   // int  [50000]
#define WS_WTH   15000000   // bf16 [64][256]        32,768
#define WS_WTL   15040000   // bf16 [64][256]        32,768
#define WS_ESRC  15080000   // fp32 [50000]
#define WS_EDST  15280000   // fp32 [50000]
#define WS_BMAX  15480000   // fp32 [3125]
#define WS_BSUM  15496000   // fp32 [3125]
#define WS_BTOT  15512000   // int  [196]
#define WS_BBASE 15513000   // int  [196]
#define WS_M     15514000
#define WS_Z     15514004
#define WS_FLAGS 15514008   // int[2]: {edge_is_i64, float_is_f32}

// ---------- dtype-flexible helpers ----------
__device__ __forceinline__ float loadf(const void* p, size_t i, int isf32) {
    return isf32 ? ((const float*)p)[i]
                 : __bfloat162float(((const __hip_bfloat16*)p)[i]);
}
__device__ __forceinline__ void load_edge(const int* __restrict__ ei, int i, int f64,
                                          int& s, int& d) {
    if (f64) { s = ei[2 * i]; d = ei[2 * (N_EDGES + i)]; }
    else     { s = ei[i];     d = ei[N_EDGES + i]; }
    s = min(max(s, 0), N_NODES - 1);
    d = min(max(d, 0), N_NODES - 1);
}

// ---------- K0: detect edge int64 and float fp32 ----------
__global__ __launch_bounds__(256) void k_flags(const int* __restrict__ ei,
                                               const unsigned* __restrict__ xw,
                                               int* __restrict__ flags) {
    int t = threadIdx.x;
    int v = 0;
    for (int i = t; i < 2048; i += 256) v |= ei[2 * i + 1];
    unsigned lo = xw[t] & 0xFFFFu;
    unsigned e8 = (lo >> 7) & 0xFFu;
    int hit = (e8 >= 96u && e8 <= 144u) ? 1 : 0;
#pragma unroll
    for (int off = 32; off > 0; off >>= 1) {
        v |= __shfl_down(v, off);
        hit += __shfl_down(hit, off);
    }
    __shared__ int sv[4], sh[4];
    if ((t & 63) == 0) { sv[t >> 6] = v; sh[t >> 6] = hit; }
    __syncthreads();
    if (t == 0) {
        flags[0] = ((sv[0] | sv[1] | sv[2] | sv[3]) == 0) ? 1 : 0;
        flags[1] = ((sh[0] + sh[1] + sh[2] + sh[3]) < 192) ? 1 : 0;
    }
}

// ---------- K1: Wt hi/lo split-transpose ----------
__global__ __launch_bounds__(256) void k_prep(const void* __restrict__ Wv,
                                              const int* __restrict__ flags,
                                              __bf16* __restrict__ Wth,
                                              __bf16* __restrict__ Wtl) {
    int isf = flags[1];
    int t = blockIdx.x * 256 + threadIdx.x;   // 0..16383
    int c = t >> 8, k = t & 255;
    float w = loadf(Wv, (size_t)k * OUT_CH + c, isf);
    __bf16 h = (__bf16)w;
    Wth[t] = h;
    Wtl[t] = (__bf16)(w - (float)h);
}

// ---------- K2: wh = x @ W via split-bf16 MFMA + fused fp32 logits ----------
__global__ __launch_bounds__(256) void k_mm(const void* __restrict__ xv,
                                            const __bf16* __restrict__ Wth,
                                            const __bf16* __restrict__ Wtl,
                                            const void* __restrict__ av,
                                            const int* __restrict__ flags,
                                            __bf16* __restrict__ whb,
                                            float* __restrict__ esrc,
                                            float* __restrict__ edst) {
    int isf = flags[1];
    int gw = (blockIdx.x * 256 + (int)threadIdx.x) >> 6;
    if (gw >= N_NODES / 16) return;           // wave-uniform
    int lane = threadIdx.x & 63;
    int m = lane & 15, quad = lane >> 4;
    int nb = gw * 16;

    floatx4 acc[4];
#pragma unroll
    for (int ct = 0; ct < 4; ++ct) acc[ct] = (floatx4){0.f, 0.f, 0.f, 0.f};

#pragma unroll
    for (int s = 0; s < 8; ++s) {
        int k0 = s * 32 + quad * 8;
        bfvec8 ahi, alo;
        if (isf) {
            const float* xr = (const float*)xv + (size_t)(nb + m) * IN_CH + k0;
            float v[8];
            *(floatx4*)(v)     = *(const floatx4*)(xr);
            *(floatx4*)(v + 4) = *(const floatx4*)(xr + 4);
#pragma unroll
            for (int j = 0; j < 8; ++j) {
                __bf16 h = (__bf16)v[j];
                ahi[j] = h;
                alo[j] = (__bf16)(v[j] - (float)h);
            }
        } else {
            ahi = *(const bfvec8*)((const __bf16*)xv + (size_t)(nb + m) * IN_CH + k0);
#pragma unroll
            for (int j = 0; j < 8; ++j) alo[j] = (__bf16)0.0f;
        }
#pragma unroll
        for (int ct = 0; ct < 4; ++ct) {
            bfvec8 bhi = *(const bfvec8*)(Wth + (ct * 16 + m) * IN_CH + k0);
            bfvec8 blo = *(const bfvec8*)(Wtl + (ct * 16 + m) * IN_CH + k0);
            acc[ct] = __builtin_amdgcn_mfma_f32_16x16x32_bf16(ahi, blo, acc[ct], 0, 0, 0);
            acc[ct] = __builtin_amdgcn_mfma_f32_16x16x32_bf16(alo, bhi, acc[ct], 0, 0, 0);
            acc[ct] = __builtin_amdgcn_mfma_f32_16x16x32_bf16(ahi, bhi, acc[ct], 0, 0, 0);
        }
    }

    float a1[4], a2[4];
#pragma unroll
    for (int ct = 0; ct < 4; ++ct) {
        a1[ct] = loadf(av, ct * 16 + m, isf);
        a2[ct] = loadf(av, OUT_CH + ct * 16 + m, isf);
    }
#pragma unroll
    for (int r = 0; r < 4; ++r) {
        int node = nb + quad * 4 + r;
        float s1 = 0.f, s2 = 0.f;
#pragma unroll
        for (int ct = 0; ct < 4; ++ct) {
            float vv = acc[ct][r];
            whb[(size_t)node * OUT_CH + ct * 16 + m] = (__bf16)vv;
            s1 += vv * a1[ct];
            s2 += vv * a2[ct];
        }
#pragma unroll
        for (int off = 1; off < 16; off <<= 1) {
            s1 += __shfl_xor(s1, off);
            s2 += __shfl_xor(s2, off);
        }
        if (m == 0) { esrc[node] = s1; edst[node] = s2; }
    }
}

// ---------- K3: u16 idx + filtered histogram + block max ----------
__global__ __launch_bounds__(256) void k_edge(const int* __restrict__ ei,
                                              const int* __restrict__ flags,
                                              const float* __restrict__ esrc,
                                              const float* __restrict__ edst,
                                              unsigned short* __restrict__ src16,
                                              unsigned short* __restrict__ dst16,
                                              int* __restrict__ cnt,
                                              float* __restrict__ bmax) {
    int f64 = flags[0];
    int i = blockIdx.x * 256 + threadIdx.x;
    int s, d;
    load_edge(ei, i, f64, s, d);
    src16[i] = (unsigned short)s;
    dst16[i] = (unsigned short)d;
    float v = esrc[s] + edst[d];
    float ev = v > 0.0f ? v : NEG_BIG;
    if (v > 0.0f) atomicAdd(&cnt[d], 1);
    float mx = ev;
#pragma unroll
    for (int off = 32; off > 0; off >>= 1) mx = fmaxf(mx, __shfl_down(mx, off));
    __shared__ float sm[4];
    if ((threadIdx.x & 63) == 0) sm[threadIdx.x >> 6] = mx;
    __syncthreads();
    if (threadIdx.x == 0)
        bmax[blockIdx.x] = fmaxf(fmaxf(sm[0], sm[1]), fmaxf(sm[2], sm[3]));
}

// ---------- K4a: per-block scan of cnt (196 blocks) ----------
__global__ __launch_bounds__(256) void k_scanA(const int* __restrict__ cnt,
                                               int* __restrict__ rowptr,
                                               int* __restrict__ btot) {
    int t = threadIdx.x, lane = t & 63, wid = t >> 6;
    int idx = blockIdx.x * 256 + t;
    int v = (idx < N_NODES) ? cnt[idx] : 0;
    int incl = v;
#pragma unroll
    for (int off = 1; off < 64; off <<= 1) {
        int u = __shfl_up(incl, off);
        if (lane >= off) incl += u;
    }
    __shared__ int wsum[4];
    if (lane == 63) wsum[wid] = incl;
    __syncthreads();
    int wbase = 0;
#pragma unroll
    for (int w = 0; w < 4; ++w) if (w < wid) wbase += wsum[w];
    if (idx < N_NODES) rowptr[idx] = wbase + incl - v;
    if (t == 255) btot[blockIdx.x] = wbase + incl;
}

// ---------- K4b: scan 196 block totals + bmax -> M ----------
__global__ __launch_bounds__(256) void k_scanB(const int* __restrict__ btot,
                                               int* __restrict__ bbase,
                                               const float* __restrict__ bmax,
                                               float* __restrict__ M) {
    int t = threadIdx.x, lane = t & 63, wid = t >> 6;
    float mx = NEG_BIG;
    for (int i = t; i < NBLK_E; i += 256) mx = fmaxf(mx, bmax[i]);
#pragma unroll
    for (int off = 32; off > 0; off >>= 1) mx = fmaxf(mx, __shfl_down(mx, off));
    __shared__ float smax[4];
    if (lane == 0) smax[wid] = mx;

    int v = (t < NBLK_N) ? btot[t] : 0;
    int incl = v;
#pragma unroll
    for (int off = 1; off < 64; off <<= 1) {
        int u = __shfl_up(incl, off);
        if (lane >= off) incl += u;
    }
    __shared__ int wsum[4];
    if (lane == 63) wsum[wid] = incl;
    __syncthreads();
    int wbase = 0;
#pragma unroll
    for (int w = 0; w < 4; ++w) if (w < wid) wbase += wsum[w];
    if (t < NBLK_N) bbase[t] = wbase + incl - v;
    if (t == 0) *M = fmaxf(fmaxf(smax[0], smax[1]), fmaxf(smax[2], smax[3]));
}

// ---------- K4c: add block bases ----------
__global__ __launch_bounds__(256) void k_scanC(int* __restrict__ rowptr,
                                               int* __restrict__ wofs,
                                               const int* __restrict__ bbase) {
    int idx = blockIdx.x * 256 + threadIdx.x;
    if (idx < N_NODES) {
        int r = rowptr[idx] + bbase[blockIdx.x];
        rowptr[idx] = r;
        wofs[idx] = r;
    }
}

// ---------- K5: exp (recomputed scores) + block sum + CSR placement ----------
__global__ __launch_bounds__(256) void k_exp(const float* __restrict__ Mp,
                                             const float* __restrict__ esrc,
                                             const float* __restrict__ edst,
                                             const unsigned short* __restrict__ src16,
                                             const unsigned short* __restrict__ dst16,
                                             int* __restrict__ wofs,
                                             float* __restrict__ w32,
                                             unsigned short* __restrict__ psrc,
                                             float* __restrict__ bsum) {
    float M = *Mp;
    int i = blockIdx.x * 256 + threadIdx.x;
    int s = src16[i], d = dst16[i];
    float v = esrc[s] + edst[d];
    float ev = v > 0.0f ? v : NEG_BIG;
    float t = expf(ev - M);          // masked edges: exp(-9e15-M) == 0
    if (v > 0.0f) {
        int pos = atomicAdd(&wofs[d], 1);
        w32[pos] = t;
        psrc[pos] = (unsigned short)s;
    }
#pragma unroll
    for (int off = 32; off > 0; off >>= 1) t += __shfl_down(t, off);
    __shared__ float sm[4];
    if ((threadIdx.x & 63) == 0) sm[threadIdx.x >> 6] = t;
    __syncthreads();
    if (threadIdx.x == 0) bsum[blockIdx.x] = sm[0] + sm[1] + sm[2] + sm[3];
}

// ---------- K6: reduce block sums -> Z ----------
__global__ __launch_bounds__(256) void k_rsum(const float* __restrict__ bsum,
                                              float* __restrict__ Z) {
    float s = 0.0f;
    for (int i = threadIdx.x; i < NBLK_E; i += 256) s += bsum[i];
#pragma unroll
    for (int off = 32; off > 0; off >>= 1) s += __shfl_down(s, off);
    __shared__ float sm[4];
    if ((threadIdx.x & 63) == 0) sm[threadIdx.x >> 6] = s;
    __syncthreads();
    if (threadIdx.x == 0) *Z = sm[0] + sm[1] + sm[2] + sm[3];
}

// ---------- K7: CSR gather, wave per dst node, lane = channel; fused ELU ----------
__global__ __launch_bounds__(256) void k_gather(const int* __restrict__ rowptr,
                                                const int* __restrict__ wofs,
                                                const float* __restrict__ w32,
                                                const unsigned short* __restrict__ psrc,
                                                const __bf16* __restrict__ whb,
                                                const float* __restrict__ Zp,
                                                float* __restrict__ out) {
    int gw = (blockIdx.x * 256 + (int)threadIdx.x) >> 6;   // dst node
    int c = threadIdx.x & 63;
    int beg = rowptr[gw];
    int end = wofs[gw];
    float Z = *Zp;
    float invZ = (Z > 0.0f) ? 1.0f / Z : 0.0f;
    float acc = 0.0f;
    for (int j = beg; j < end; ++j) {
        float t = w32[j];
        int s = psrc[j];
        acc += t * (float)whb[(size_t)s * OUT_CH + c];
    }
    float h = acc * invZ;
    out[(size_t)gw * OUT_CH + c] = h > 0.0f ? h : expf(h) - 1.0f;
}

extern "C" void kernel_launch(void* const* d_in, const int* in_sizes, int n_in,
                              void* d_out, int out_size, void* d_ws, size_t ws_size,
                              hipStream_t stream) {
    const void* x  = d_in[0];
    const int* ei  = (const int*)d_in[1];
    const void* W  = d_in[2];
    const void* a  = d_in[3];
    float* out     = (float*)d_out;

    char* ws = (char*)d_ws;
    __bf16* whb  = (__bf16*)(ws + WS_WHB);
    float* w32   = (float*)(ws + WS_W32);
    unsigned short* psrc  = (unsigned short*)(ws + WS_PSRC);
    unsigned short* src16 = (unsigned short*)(ws + WS_SRC16);
    unsigned short* dst16 = (unsigned short*)(ws + WS_DST16);
    int* cnt     = (int*)(ws + WS_CNT);
    int* rowptr  = (int*)(ws + WS_ROWP);
    int* wofs    = (int*)(ws + WS_WOFS);
    __bf16* Wth  = (__bf16*)(ws + WS_WTH);
    __bf16* Wtl  = (__bf16*)(ws + WS_WTL);
    float* esrc  = (float*)(ws + WS_ESRC);
    float* edst  = (float*)(ws + WS_EDST);
    float* bmax  = (float*)(ws + WS_BMAX);
    float* bsum  = (float*)(ws + WS_BSUM);
    int*   btot  = (int*)(ws + WS_BTOT);
    int*   bbase = (int*)(ws + WS_BBASE);
    float* M     = (float*)(ws + WS_M);
    float* Z     = (float*)(ws + WS_Z);
    int*   flags = (int*)(ws + WS_FLAGS);

    hipMemsetAsync(cnt, 0, N_NODES * sizeof(int), stream);

    k_flags <<<1,      256, 0, stream>>>(ei, (const unsigned*)x, flags);
    k_prep  <<<64,     256, 0, stream>>>(W, flags, Wth, Wtl);
    k_mm    <<<782,    256, 0, stream>>>(x, Wth, Wtl, a, flags, whb, esrc, edst);
    k_edge  <<<NBLK_E, 256, 0, stream>>>(ei, flags, esrc, edst, src16, dst16, cnt, bmax);
    k_scanA <<<NBLK_N, 256, 0, stream>>>(cnt, rowptr, btot);
    k_scanB <<<1,      256, 0, stream>>>(btot, bbase, bmax, M);
    k_scanC <<<NBLK_N, 256, 0, stream>>>(rowptr, wofs, bbase);
    k_exp   <<<NBLK_E, 256, 0, stream>>>(M, esrc, edst, src16, dst16, wofs, w32, psrc, bsum);
    k_rsum  <<<1,      256, 0, stream>>>(bsum, Z);
    k_gather<<<N_NODES / 4, 256, 0, stream>>>(rowptr, wofs, w32, psrc, whb, Z, out);
}

// Round 8
// 213.090 us; speedup vs baseline: 1.5604x; 1.1093x over previous
//
#include <hip/hip_runtime.h>
#include <hip/hip_bf16.h>

#define N_NODES 50000
#define N_EDGES 800000
#define IN_CH 256
#define OUT_CH 64
#define NEG_BIG -9e15f
#define NBLK_E 3125   // N_EDGES / 256
#define NBLK_N 196    // ceil(50000/256)

typedef __bf16 bfvec8 __attribute__((ext_vector_type(8)));
typedef float floatx4 __attribute__((ext_vector_type(4)));

// ---- ws layout (bytes), total ~15.5 MB ----
#define WS_WHB   0          // bf16 [50000][64]   6,400,000
#define WS_W32   6400000    // fp32 [800000]      3,200,000  sorted exp weights
#define WS_PSRC  9600000    // u16  [800000]      1,600,000  sorted src
#define WS_SRC16 11200000   // u16  [800000]      1,600,000
#define WS_DST16 12800000   // u16  [800000]      1,600,000
#define WS_CNT   14400000   // int  [50000]
#define WS_ROWP  14600000   // int  [50000]
#define WS_WOFS  14800000   // int  [50000]
#define WS_WTH   15000000   // bf16 [64][256]        32,768
#define WS_WTL   15040000   // bf16 [64][256]        32,768
#define WS_ESRC  15080000   // fp32 [50000]
#define WS_EDST  15280000   // fp32 [50000]
#define WS_BMAX  15480000   // fp32 [3125]
#define WS_BSUM  15496000   // fp32 [3125]
#define WS_BTOT  15512000   // int  [196]
#define WS_BBASE 15513000   // int  [196]
#define WS_M     15514000
#define WS_Z     15514004
#define WS_FLAGS 15514008   // int[2]: {edge_is_i64, float_is_f32}

// ---------- dtype-flexible helpers ----------
__device__ __forceinline__ float loadf(const void* p, size_t i, int isf32) {
    return isf32 ? ((const float*)p)[i]
                 : __bfloat162float(((const __hip_bfloat16*)p)[i]);
}
__device__ __forceinline__ void load_edge(const int* __restrict__ ei, int i, int f64,
                                          int& s, int& d) {
    if (f64) {
        int2 ps = ((const int2*)ei)[i];
        int2 pd = ((const int2*)ei)[N_EDGES + i];
        s = ps.x; d = pd.x;
    } else {
        s = ei[i]; d = ei[N_EDGES + i];
    }
    s = min(max(s, 0), N_NODES - 1);
    d = min(max(d, 0), N_NODES - 1);
}

// ---------- K0: detect edge int64 and float fp32 ----------
__global__ __launch_bounds__(256) void k_flags(const int* __restrict__ ei,
                                               const unsigned* __restrict__ xw,
                                               int* __restrict__ flags) {
    int t = threadIdx.x;
    int v = 0;
    for (int i = t; i < 2048; i += 256) v |= ei[2 * i + 1];
    unsigned lo = xw[t] & 0xFFFFu;
    unsigned e8 = (lo >> 7) & 0xFFu;
    int hit = (e8 >= 96u && e8 <= 144u) ? 1 : 0;
#pragma unroll
    for (int off = 32; off > 0; off >>= 1) {
        v |= __shfl_down(v, off);
        hit += __shfl_down(hit, off);
    }
    __shared__ int sv[4], sh[4];
    if ((t & 63) == 0) { sv[t >> 6] = v; sh[t >> 6] = hit; }
    __syncthreads();
    if (t == 0) {
        flags[0] = ((sv[0] | sv[1] | sv[2] | sv[3]) == 0) ? 1 : 0;
        flags[1] = ((sh[0] + sh[1] + sh[2] + sh[3]) < 192) ? 1 : 0;
    }
}

// ---------- K1: Wt hi/lo split-transpose ----------
__global__ __launch_bounds__(256) void k_prep(const void* __restrict__ Wv,
                                              const int* __restrict__ flags,
                                              __bf16* __restrict__ Wth,
                                              __bf16* __restrict__ Wtl) {
    int isf = flags[1];
    int t = blockIdx.x * 256 + threadIdx.x;   // 0..16383
    int c = t >> 8, k = t & 255;
    float w = loadf(Wv, (size_t)k * OUT_CH + c, isf);
    __bf16 h = (__bf16)w;
    Wth[t] = h;
    Wtl[t] = (__bf16)(w - (float)h);
}

// ---------- K2: wh = x @ W via split-bf16 MFMA + fused fp32 logits ----------
__global__ __launch_bounds__(256) void k_mm(const void* __restrict__ xv,
                                            const __bf16* __restrict__ Wth,
                                            const __bf16* __restrict__ Wtl,
                                            const void* __restrict__ av,
                                            const int* __restrict__ flags,
                                            __bf16* __restrict__ whb,
                                            float* __restrict__ esrc,
                                            float* __restrict__ edst) {
    int isf = flags[1];
    int gw = (blockIdx.x * 256 + (int)threadIdx.x) >> 6;
    if (gw >= N_NODES / 16) return;           // wave-uniform
    int lane = threadIdx.x & 63;
    int m = lane & 15, quad = lane >> 4;
    int nb = gw * 16;

    floatx4 acc[4];
#pragma unroll
    for (int ct = 0; ct < 4; ++ct) acc[ct] = (floatx4){0.f, 0.f, 0.f, 0.f};

#pragma unroll
    for (int s = 0; s < 8; ++s) {
        int k0 = s * 32 + quad * 8;
        bfvec8 ahi, alo;
        if (isf) {
            const float* xr = (const float*)xv + (size_t)(nb + m) * IN_CH + k0;
            float v[8];
            *(floatx4*)(v)     = *(const floatx4*)(xr);
            *(floatx4*)(v + 4) = *(const floatx4*)(xr + 4);
#pragma unroll
            for (int j = 0; j < 8; ++j) {
                __bf16 h = (__bf16)v[j];
                ahi[j] = h;
                alo[j] = (__bf16)(v[j] - (float)h);
            }
        } else {
            ahi = *(const bfvec8*)((const __bf16*)xv + (size_t)(nb + m) * IN_CH + k0);
#pragma unroll
            for (int j = 0; j < 8; ++j) alo[j] = (__bf16)0.0f;
        }
#pragma unroll
        for (int ct = 0; ct < 4; ++ct) {
            bfvec8 bhi = *(const bfvec8*)(Wth + (ct * 16 + m) * IN_CH + k0);
            bfvec8 blo = *(const bfvec8*)(Wtl + (ct * 16 + m) * IN_CH + k0);
            acc[ct] = __builtin_amdgcn_mfma_f32_16x16x32_bf16(ahi, blo, acc[ct], 0, 0, 0);
            acc[ct] = __builtin_amdgcn_mfma_f32_16x16x32_bf16(alo, bhi, acc[ct], 0, 0, 0);
            acc[ct] = __builtin_amdgcn_mfma_f32_16x16x32_bf16(ahi, bhi, acc[ct], 0, 0, 0);
        }
    }

    float a1[4], a2[4];
#pragma unroll
    for (int ct = 0; ct < 4; ++ct) {
        a1[ct] = loadf(av, ct * 16 + m, isf);
        a2[ct] = loadf(av, OUT_CH + ct * 16 + m, isf);
    }
#pragma unroll
    for (int r = 0; r < 4; ++r) {
        int node = nb + quad * 4 + r;
        float s1 = 0.f, s2 = 0.f;
#pragma unroll
        for (int ct = 0; ct < 4; ++ct) {
            float vv = acc[ct][r];
            whb[(size_t)node * OUT_CH + ct * 16 + m] = (__bf16)vv;
            s1 += vv * a1[ct];
            s2 += vv * a2[ct];
        }
#pragma unroll
        for (int off = 1; off < 16; off <<= 1) {
            s1 += __shfl_xor(s1, off);
            s2 += __shfl_xor(s2, off);
        }
        if (m == 0) { esrc[node] = s1; edst[node] = s2; }
    }
}

// ---------- K3: u16 idx + filtered histogram + block max ----------
__global__ __launch_bounds__(256) void k_edge(const int* __restrict__ ei,
                                              const int* __restrict__ flags,
                                              const float* __restrict__ esrc,
                                              const float* __restrict__ edst,
                                              unsigned short* __restrict__ src16,
                                              unsigned short* __restrict__ dst16,
                                              int* __restrict__ cnt,
                                              float* __restrict__ bmax) {
    int f64 = flags[0];
    int i = blockIdx.x * 256 + threadIdx.x;
    int s, d;
    load_edge(ei, i, f64, s, d);
    src16[i] = (unsigned short)s;
    dst16[i] = (unsigned short)d;
    float v = esrc[s] + edst[d];
    float ev = v > 0.0f ? v : NEG_BIG;
    if (v > 0.0f) atomicAdd(&cnt[d], 1);
    float mx = ev;
#pragma unroll
    for (int off = 32; off > 0; off >>= 1) mx = fmaxf(mx, __shfl_down(mx, off));
    __shared__ float sm[4];
    if ((threadIdx.x & 63) == 0) sm[threadIdx.x >> 6] = mx;
    __syncthreads();
    if (threadIdx.x == 0)
        bmax[blockIdx.x] = fmaxf(fmaxf(sm[0], sm[1]), fmaxf(sm[2], sm[3]));
}

// ---------- K4a: per-block scan of cnt (196 blocks) ----------
__global__ __launch_bounds__(256) void k_scanA(const int* __restrict__ cnt,
                                               int* __restrict__ rowptr,
                                               int* __restrict__ btot) {
    int t = threadIdx.x, lane = t & 63, wid = t >> 6;
    int idx = blockIdx.x * 256 + t;
    int v = (idx < N_NODES) ? cnt[idx] : 0;
    int incl = v;
#pragma unroll
    for (int off = 1; off < 64; off <<= 1) {
        int u = __shfl_up(incl, off);
        if (lane >= off) incl += u;
    }
    __shared__ int wsum[4];
    if (lane == 63) wsum[wid] = incl;
    __syncthreads();
    int wbase = 0;
#pragma unroll
    for (int w = 0; w < 4; ++w) if (w < wid) wbase += wsum[w];
    if (idx < N_NODES) rowptr[idx] = wbase + incl - v;
    if (t == 255) btot[blockIdx.x] = wbase + incl;
}

// ---------- K4b: scan 196 block totals + bmax -> M ----------
__global__ __launch_bounds__(256) void k_scanB(const int* __restrict__ btot,
                                               int* __restrict__ bbase,
                                               const float* __restrict__ bmax,
                                               float* __restrict__ M) {
    int t = threadIdx.x, lane = t & 63, wid = t >> 6;
    float mx = NEG_BIG;
    for (int i = t; i < NBLK_E; i += 256) mx = fmaxf(mx, bmax[i]);
#pragma unroll
    for (int off = 32; off > 0; off >>= 1) mx = fmaxf(mx, __shfl_down(mx, off));
    __shared__ float smax[4];
    if (lane == 0) smax[wid] = mx;

    int v = (t < NBLK_N) ? btot[t] : 0;
    int incl = v;
#pragma unroll
    for (int off = 1; off < 64; off <<= 1) {
        int u = __shfl_up(incl, off);
        if (lane >= off) incl += u;
    }
    __shared__ int wsum[4];
    if (lane == 63) wsum[wid] = incl;
    __syncthreads();
    int wbase = 0;
#pragma unroll
    for (int w = 0; w < 4; ++w) if (w < wid) wbase += wsum[w];
    if (t < NBLK_N) bbase[t] = wbase + incl - v;
    if (t == 0) *M = fmaxf(fmaxf(smax[0], smax[1]), fmaxf(smax[2], smax[3]));
}

// ---------- K4c: add block bases ----------
__global__ __launch_bounds__(256) void k_scanC(int* __restrict__ rowptr,
                                               int* __restrict__ wofs,
                                               const int* __restrict__ bbase) {
    int idx = blockIdx.x * 256 + threadIdx.x;
    if (idx < N_NODES) {
        int r = rowptr[idx] + bbase[blockIdx.x];
        rowptr[idx] = r;
        wofs[idx] = r;
    }
}

// ---------- K5: exp (recomputed scores) + block sum + CSR placement ----------
__global__ __launch_bounds__(256) void k_exp(const float* __restrict__ Mp,
                                             const float* __restrict__ esrc,
                                             const float* __restrict__ edst,
                                             const unsigned short* __restrict__ src16,
                                             const unsigned short* __restrict__ dst16,
                                             int* __restrict__ wofs,
                                             float* __restrict__ w32,
                                             unsigned short* __restrict__ psrc,
                                             float* __restrict__ bsum) {
    float M = *Mp;
    int i = blockIdx.x * 256 + threadIdx.x;
    int s = src16[i], d = dst16[i];
    float v = esrc[s] + edst[d];
    float ev = v > 0.0f ? v : NEG_BIG;
    float t = expf(ev - M);          // masked edges: exp(-9e15-M) == 0
    if (v > 0.0f) {
        int pos = atomicAdd(&wofs[d], 1);
        w32[pos] = t;
        psrc[pos] = (unsigned short)s;
    }
#pragma unroll
    for (int off = 32; off > 0; off >>= 1) t += __shfl_down(t, off);
    __shared__ float sm[4];
    if ((threadIdx.x & 63) == 0) sm[threadIdx.x >> 6] = t;
    __syncthreads();
    if (threadIdx.x == 0) bsum[blockIdx.x] = sm[0] + sm[1] + sm[2] + sm[3];
}

// ---------- K6: reduce block sums -> Z ----------
__global__ __launch_bounds__(256) void k_rsum(const float* __restrict__ bsum,
                                              float* __restrict__ Z) {
    float s = 0.0f;
    for (int i = threadIdx.x; i < NBLK_E; i += 256) s += bsum[i];
#pragma unroll
    for (int off = 32; off > 0; off >>= 1) s += __shfl_down(s, off);
    __shared__ float sm[4];
    if ((threadIdx.x & 63) == 0) sm[threadIdx.x >> 6] = s;
    __syncthreads();
    if (threadIdx.x == 0) *Z = sm[0] + sm[1] + sm[2] + sm[3];
}

// ---------- K7: CSR gather, wave per dst node, 8 edges in flight ----------
// lane = sub*8 + cg: sub = edge slot (0..7), cg = channel group (8 ch each)
__global__ __launch_bounds__(256) void k_gather(const int* __restrict__ rowptr,
                                                const int* __restrict__ wofs,
                                                const float* __restrict__ w32,
                                                const unsigned short* __restrict__ psrc,
                                                const __bf16* __restrict__ whb,
                                                const float* __restrict__ Zp,
                                                float* __restrict__ out) {
    int gw = (blockIdx.x * 256 + (int)threadIdx.x) >> 6;   // dst node
    int lane = threadIdx.x & 63;
    int sub = lane >> 3;          // edge slot
    int cg  = lane & 7;           // channel group
    int beg = rowptr[gw];
    int end = wofs[gw];
    float Z = *Zp;
    float invZ = (Z > 0.0f) ? 1.0f / Z : 0.0f;

    float acc[8];
#pragma unroll
    for (int k = 0; k < 8; ++k) acc[k] = 0.0f;

    for (int j0 = beg; j0 < end; j0 += 8) {
        int j = j0 + sub;
        bool valid = j < end;
        int jj = valid ? j : beg;
        float t = valid ? w32[jj] : 0.0f;
        int s = psrc[jj];
        bfvec8 v = *(const bfvec8*)(whb + (size_t)s * OUT_CH + cg * 8);
#pragma unroll
        for (int k = 0; k < 8; ++k) acc[k] += t * (float)v[k];
    }

    // reduce the 8 edge slots (lanes sharing cg): xor bits 3,4,5
#pragma unroll
    for (int mask = 8; mask <= 32; mask <<= 1) {
#pragma unroll
        for (int k = 0; k < 8; ++k) acc[k] += __shfl_xor(acc[k], mask);
    }

    if (sub == 0) {
        floatx4 o0, o1;
#pragma unroll
        for (int k = 0; k < 4; ++k) {
            float h = acc[k] * invZ;
            o0[k] = h > 0.0f ? h : expf(h) - 1.0f;
        }
#pragma unroll
        for (int k = 0; k < 4; ++k) {
            float h = acc[4 + k] * invZ;
            o1[k] = h > 0.0f ? h : expf(h) - 1.0f;
        }
        float* dst = out + (size_t)gw * OUT_CH + cg * 8;
        *(floatx4*)(dst)     = o0;
        *(floatx4*)(dst + 4) = o1;
    }
}

extern "C" void kernel_launch(void* const* d_in, const int* in_sizes, int n_in,
                              void* d_out, int out_size, void* d_ws, size_t ws_size,
                              hipStream_t stream) {
    const void* x  = d_in[0];
    const int* ei  = (const int*)d_in[1];
    const void* W  = d_in[2];
    const void* a  = d_in[3];
    float* out     = (float*)d_out;

    char* ws = (char*)d_ws;
    __bf16* whb  = (__bf16*)(ws + WS_WHB);
    float* w32   = (float*)(ws + WS_W32);
    unsigned short* psrc  = (unsigned short*)(ws + WS_PSRC);
    unsigned short* src16 = (unsigned short*)(ws + WS_SRC16);
    unsigned short* dst16 = (unsigned short*)(ws + WS_DST16);
    int* cnt     = (int*)(ws + WS_CNT);
    int* rowptr  = (int*)(ws + WS_ROWP);
    int* wofs    = (int*)(ws + WS_WOFS);
    __bf16* Wth  = (__bf16*)(ws + WS_WTH);
    __bf16* Wtl  = (__bf16*)(ws + WS_WTL);
    float* esrc  = (float*)(ws + WS_ESRC);
    float* edst  = (float*)(ws + WS_EDST);
    float* bmax  = (float*)(ws + WS_BMAX);
    float* bsum  = (float*)(ws + WS_BSUM);
    int*   btot  = (int*)(ws + WS_BTOT);
    int*   bbase = (int*)(ws + WS_BBASE);
    float* M     = (float*)(ws + WS_M);
    float* Z     = (float*)(ws + WS_Z);
    int*   flags = (int*)(ws + WS_FLAGS);

    hipMemsetAsync(cnt, 0, N_NODES * sizeof(int), stream);

    k_flags <<<1,      256, 0, stream>>>(ei, (const unsigned*)x, flags);
    k_prep  <<<64,     256, 0, stream>>>(W, flags, Wth, Wtl);
    k_mm    <<<782,    256, 0, stream>>>(x, Wth, Wtl, a, flags, whb, esrc, edst);
    k_edge  <<<NBLK_E, 256, 0, stream>>>(ei, flags, esrc, edst, src16, dst16, cnt, bmax);
    k_scanA <<<NBLK_N, 256, 0, stream>>>(cnt, rowptr, btot);
    k_scanB <<<1,      256, 0, stream>>>(btot, bbase, bmax, M);
    k_scanC <<<NBLK_N, 256, 0, stream>>>(rowptr, wofs, bbase);
    k_exp   <<<NBLK_E, 256, 0, stream>>>(M, esrc, edst, src16, dst16, wofs, w32, psrc, bsum);
    k_rsum  <<<1,      256, 0, stream>>>(bsum, Z);
    k_gather<<<N_NODES / 4, 256, 0, stream>>>(rowptr, wofs, w32, psrc, whb, Z, out);
}

// Round 9
// 212.532 us; speedup vs baseline: 1.5645x; 1.0026x over previous
//
#include <hip/hip_runtime.h>
#include <hip/hip_bf16.h>

#define N_NODES 50000
#define N_EDGES 800000
#define IN_CH 256
#define OUT_CH 64
#define NEG_BIG -9e15f
#define NBLK_E 3125   // N_EDGES / 256
#define NBLK_N 196    // ceil(50000/256)

typedef __bf16 bfvec8 __attribute__((ext_vector_type(8)));
typedef float floatx4 __attribute__((ext_vector_type(4)));

// ---- ws layout (bytes), total ~15.5 MB ----
#define WS_WHB   0          // bf16 [50000][64]   6,400,000
#define WS_W32   6400000    // fp32 [800000]      3,200,000  sorted exp weights
#define WS_PSRC  9600000    // u16  [800000]      1,600,000  sorted src
#define WS_SRC16 11200000   // u16  [800000]      1,600,000
#define WS_DST16 12800000   // u16  [800000]      1,600,000
#define WS_CNT   14400000   // int  [50000]
#define WS_ROWP  14600000   // int  [50000]
#define WS_WOFS  14800000   // int  [50000]
#define WS_WTH   15000000   // bf16 [64][256]        32,768
#define WS_WTL   15040000   // bf16 [64][256]        32,768
#define WS_ESRC  15080000   // fp32 [50000]
#define WS_EDST  15280000   // fp32 [50000]
#define WS_BMAX  15480000   // fp32 [3125]
#define WS_BSUM  15496000   // fp32 [3125]
#define WS_BTOT  15512000   // int  [196]
#define WS_BBASE 15513000   // int  [196]
#define WS_M     15514000
#define WS_Z     15514004
#define WS_FLAGS 15514008   // int[2]: {edge_is_i64, float_is_f32}

// ---------- dtype-flexible helpers ----------
__device__ __forceinline__ float loadf(const void* p, size_t i, int isf32) {
    return isf32 ? ((const float*)p)[i]
                 : __bfloat162float(((const __hip_bfloat16*)p)[i]);
}
__device__ __forceinline__ void load_edge(const int* __restrict__ ei, int i, int f64,
                                          int& s, int& d) {
    if (f64) {
        int2 ps = ((const int2*)ei)[i];
        int2 pd = ((const int2*)ei)[N_EDGES + i];
        s = ps.x; d = pd.x;
    } else {
        s = ei[i]; d = ei[N_EDGES + i];
    }
    s = min(max(s, 0), N_NODES - 1);
    d = min(max(d, 0), N_NODES - 1);
}

// ---------- K0: detect edge int64 and float fp32 ----------
__global__ __launch_bounds__(256) void k_flags(const int* __restrict__ ei,
                                               const unsigned* __restrict__ xw,
                                               int* __restrict__ flags) {
    int t = threadIdx.x;
    int v = 0;
    for (int i = t; i < 2048; i += 256) v |= ei[2 * i + 1];
    unsigned lo = xw[t] & 0xFFFFu;
    unsigned e8 = (lo >> 7) & 0xFFu;
    int hit = (e8 >= 96u && e8 <= 144u) ? 1 : 0;
#pragma unroll
    for (int off = 32; off > 0; off >>= 1) {
        v |= __shfl_down(v, off);
        hit += __shfl_down(hit, off);
    }
    __shared__ int sv[4], sh[4];
    if ((t & 63) == 0) { sv[t >> 6] = v; sh[t >> 6] = hit; }
    __syncthreads();
    if (t == 0) {
        flags[0] = ((sv[0] | sv[1] | sv[2] | sv[3]) == 0) ? 1 : 0;
        flags[1] = ((sh[0] + sh[1] + sh[2] + sh[3]) < 192) ? 1 : 0;
    }
}

// ---------- K1: Wt hi/lo split-transpose ----------
__global__ __launch_bounds__(256) void k_prep(const void* __restrict__ Wv,
                                              const int* __restrict__ flags,
                                              __bf16* __restrict__ Wth,
                                              __bf16* __restrict__ Wtl) {
    int isf = flags[1];
    int t = blockIdx.x * 256 + threadIdx.x;   // 0..16383
    int c = t >> 8, k = t & 255;
    float w = loadf(Wv, (size_t)k * OUT_CH + c, isf);
    __bf16 h = (__bf16)w;
    Wth[t] = h;
    Wtl[t] = (__bf16)(w - (float)h);
}

// ---------- K2: wh = x @ W via split-bf16 MFMA + fused fp32 logits ----------
// dtype branch hoisted OUT of the K-loop; all x loads issued up-front (ILP).
__global__ __launch_bounds__(256) void k_mm(const void* __restrict__ xv,
                                            const __bf16* __restrict__ Wth,
                                            const __bf16* __restrict__ Wtl,
                                            const void* __restrict__ av,
                                            const int* __restrict__ flags,
                                            __bf16* __restrict__ whb,
                                            float* __restrict__ esrc,
                                            float* __restrict__ edst) {
    int isf = flags[1];
    int gw = (blockIdx.x * 256 + (int)threadIdx.x) >> 6;
    if (gw >= N_NODES / 16) return;           // wave-uniform
    int lane = threadIdx.x & 63;
    int m = lane & 15, quad = lane >> 4;
    int nb = gw * 16;

    floatx4 acc[4];
#pragma unroll
    for (int ct = 0; ct < 4; ++ct) acc[ct] = (floatx4){0.f, 0.f, 0.f, 0.f};

    if (isf) {
        // ---- fp32 arm: prefetch all 16 dwordx4, then convert+MFMA ----
        const float* xr = (const float*)xv + (size_t)(nb + m) * IN_CH + quad * 8;
        floatx4 x0[8], x1[8];
#pragma unroll
        for (int s = 0; s < 8; ++s) {
            x0[s] = *(const floatx4*)(xr + s * 32);
            x1[s] = *(const floatx4*)(xr + s * 32 + 4);
        }
#pragma unroll
        for (int s = 0; s < 8; ++s) {
            int k0 = s * 32 + quad * 8;
            float v[8];
            *(floatx4*)(v)     = x0[s];
            *(floatx4*)(v + 4) = x1[s];
            bfvec8 ahi, alo;
#pragma unroll
            for (int j = 0; j < 8; ++j) {
                __bf16 h = (__bf16)v[j];
                ahi[j] = h;
                alo[j] = (__bf16)(v[j] - (float)h);
            }
#pragma unroll
            for (int ct = 0; ct < 4; ++ct) {
                bfvec8 bhi = *(const bfvec8*)(Wth + (ct * 16 + m) * IN_CH + k0);
                bfvec8 blo = *(const bfvec8*)(Wtl + (ct * 16 + m) * IN_CH + k0);
                acc[ct] = __builtin_amdgcn_mfma_f32_16x16x32_bf16(ahi, blo, acc[ct], 0, 0, 0);
                acc[ct] = __builtin_amdgcn_mfma_f32_16x16x32_bf16(alo, bhi, acc[ct], 0, 0, 0);
                acc[ct] = __builtin_amdgcn_mfma_f32_16x16x32_bf16(ahi, bhi, acc[ct], 0, 0, 0);
            }
        }
    } else {
        // ---- bf16 arm: prefetch all 8 b128 loads, MFMA (no lo term) ----
        const __bf16* xr = (const __bf16*)xv + (size_t)(nb + m) * IN_CH + quad * 8;
        bfvec8 xa[8];
#pragma unroll
        for (int s = 0; s < 8; ++s) xa[s] = *(const bfvec8*)(xr + s * 32);
#pragma unroll
        for (int s = 0; s < 8; ++s) {
            int k0 = s * 32 + quad * 8;
#pragma unroll
            for (int ct = 0; ct < 4; ++ct) {
                bfvec8 bhi = *(const bfvec8*)(Wth + (ct * 16 + m) * IN_CH + k0);
                bfvec8 blo = *(const bfvec8*)(Wtl + (ct * 16 + m) * IN_CH + k0);
                acc[ct] = __builtin_amdgcn_mfma_f32_16x16x32_bf16(xa[s], blo, acc[ct], 0, 0, 0);
                acc[ct] = __builtin_amdgcn_mfma_f32_16x16x32_bf16(xa[s], bhi, acc[ct], 0, 0, 0);
            }
        }
    }

    float a1[4], a2[4];
#pragma unroll
    for (int ct = 0; ct < 4; ++ct) {
        a1[ct] = loadf(av, ct * 16 + m, isf);
        a2[ct] = loadf(av, OUT_CH + ct * 16 + m, isf);
    }
#pragma unroll
    for (int r = 0; r < 4; ++r) {
        int node = nb + quad * 4 + r;
        float s1 = 0.f, s2 = 0.f;
#pragma unroll
        for (int ct = 0; ct < 4; ++ct) {
            float vv = acc[ct][r];
            whb[(size_t)node * OUT_CH + ct * 16 + m] = (__bf16)vv;
            s1 += vv * a1[ct];
            s2 += vv * a2[ct];
        }
#pragma unroll
        for (int off = 1; off < 16; off <<= 1) {
            s1 += __shfl_xor(s1, off);
            s2 += __shfl_xor(s2, off);
        }
        if (m == 0) { esrc[node] = s1; edst[node] = s2; }
    }
}

// ---------- K3: u16 idx + filtered histogram + block max ----------
__global__ __launch_bounds__(256) void k_edge(const int* __restrict__ ei,
                                              const int* __restrict__ flags,
                                              const float* __restrict__ esrc,
                                              const float* __restrict__ edst,
                                              unsigned short* __restrict__ src16,
                                              unsigned short* __restrict__ dst16,
                                              int* __restrict__ cnt,
                                              float* __restrict__ bmax) {
    int f64 = flags[0];
    int i = blockIdx.x * 256 + threadIdx.x;
    int s, d;
    load_edge(ei, i, f64, s, d);
    src16[i] = (unsigned short)s;
    dst16[i] = (unsigned short)d;
    float v = esrc[s] + edst[d];
    float ev = v > 0.0f ? v : NEG_BIG;
    if (v > 0.0f) atomicAdd(&cnt[d], 1);
    float mx = ev;
#pragma unroll
    for (int off = 32; off > 0; off >>= 1) mx = fmaxf(mx, __shfl_down(mx, off));
    __shared__ float sm[4];
    if ((threadIdx.x & 63) == 0) sm[threadIdx.x >> 6] = mx;
    __syncthreads();
    if (threadIdx.x == 0)
        bmax[blockIdx.x] = fmaxf(fmaxf(sm[0], sm[1]), fmaxf(sm[2], sm[3]));
}

// ---------- K4a: per-block scan of cnt (196 blocks) ----------
__global__ __launch_bounds__(256) void k_scanA(const int* __restrict__ cnt,
                                               int* __restrict__ rowptr,
                                               int* __restrict__ btot) {
    int t = threadIdx.x, lane = t & 63, wid = t >> 6;
    int idx = blockIdx.x * 256 + t;
    int v = (idx < N_NODES) ? cnt[idx] : 0;
    int incl = v;
#pragma unroll
    for (int off = 1; off < 64; off <<= 1) {
        int u = __shfl_up(incl, off);
        if (lane >= off) incl += u;
    }
    __shared__ int wsum[4];
    if (lane == 63) wsum[wid] = incl;
    __syncthreads();
    int wbase = 0;
#pragma unroll
    for (int w = 0; w < 4; ++w) if (w < wid) wbase += wsum[w];
    if (idx < N_NODES) rowptr[idx] = wbase + incl - v;
    if (t == 255) btot[blockIdx.x] = wbase + incl;
}

// ---------- K4b: scan 196 block totals + bmax -> M ----------
__global__ __launch_bounds__(256) void k_scanB(const int* __restrict__ btot,
                                               int* __restrict__ bbase,
                                               const float* __restrict__ bmax,
                                               float* __restrict__ M) {
    int t = threadIdx.x, lane = t & 63, wid = t >> 6;
    float mx = NEG_BIG;
    for (int i = t; i < NBLK_E; i += 256) mx = fmaxf(mx, bmax[i]);
#pragma unroll
    for (int off = 32; off > 0; off >>= 1) mx = fmaxf(mx, __shfl_down(mx, off));
    __shared__ float smax[4];
    if (lane == 0) smax[wid] = mx;

    int v = (t < NBLK_N) ? btot[t] : 0;
    int incl = v;
#pragma unroll
    for (int off = 1; off < 64; off <<= 1) {
        int u = __shfl_up(incl, off);
        if (lane >= off) incl += u;
    }
    __shared__ int wsum[4];
    if (lane == 63) wsum[wid] = incl;
    __syncthreads();
    int wbase = 0;
#pragma unroll
    for (int w = 0; w < 4; ++w) if (w < wid) wbase += wsum[w];
    if (t < NBLK_N) bbase[t] = wbase + incl - v;
    if (t == 0) *M = fmaxf(fmaxf(smax[0], smax[1]), fmaxf(smax[2], smax[3]));
}

// ---------- K4c: add block bases ----------
__global__ __launch_bounds__(256) void k_scanC(int* __restrict__ rowptr,
                                               int* __restrict__ wofs,
                                               const int* __restrict__ bbase) {
    int idx = blockIdx.x * 256 + threadIdx.x;
    if (idx < N_NODES) {
        int r = rowptr[idx] + bbase[blockIdx.x];
        rowptr[idx] = r;
        wofs[idx] = r;
    }
}

// ---------- K5: exp (recomputed scores) + block sum + CSR placement ----------
__global__ __launch_bounds__(256) void k_exp(const float* __restrict__ Mp,
                                             const float* __restrict__ esrc,
                                             const float* __restrict__ edst,
                                             const unsigned short* __restrict__ src16,
                                             const unsigned short* __restrict__ dst16,
                                             int* __restrict__ wofs,
                                             float* __restrict__ w32,
                                             unsigned short* __restrict__ psrc,
                                             float* __restrict__ bsum) {
    float M = *Mp;
    int i = blockIdx.x * 256 + threadIdx.x;
    int s = src16[i], d = dst16[i];
    float v = esrc[s] + edst[d];
    float ev = v > 0.0f ? v : NEG_BIG;
    float t = expf(ev - M);          // masked edges: exp(-9e15-M) == 0
    if (v > 0.0f) {
        int pos = atomicAdd(&wofs[d], 1);
        w32[pos] = t;
        psrc[pos] = (unsigned short)s;
    }
#pragma unroll
    for (int off = 32; off > 0; off >>= 1) t += __shfl_down(t, off);
    __shared__ float sm[4];
    if ((threadIdx.x & 63) == 0) sm[threadIdx.x >> 6] = t;
    __syncthreads();
    if (threadIdx.x == 0) bsum[blockIdx.x] = sm[0] + sm[1] + sm[2] + sm[3];
}

// ---------- K6: reduce block sums -> Z ----------
__global__ __launch_bounds__(256) void k_rsum(const float* __restrict__ bsum,
                                              float* __restrict__ Z) {
    float s = 0.0f;
    for (int i = threadIdx.x; i < NBLK_E; i += 256) s += bsum[i];
#pragma unroll
    for (int off = 32; off > 0; off >>= 1) s += __shfl_down(s, off);
    __shared__ float sm[4];
    if ((threadIdx.x & 63) == 0) sm[threadIdx.x >> 6] = s;
    __syncthreads();
    if (threadIdx.x == 0) *Z = sm[0] + sm[1] + sm[2] + sm[3];
}

// ---------- K7: CSR gather, wave per dst node, 8 edges in flight ----------
__global__ __launch_bounds__(256) void k_gather(const int* __restrict__ rowptr,
                                                const int* __restrict__ wofs,
                                                const float* __restrict__ w32,
                                                const unsigned short* __restrict__ psrc,
                                                const __bf16* __restrict__ whb,
                                                const float* __restrict__ Zp,
                                                float* __restrict__ out) {
    int gw = (blockIdx.x * 256 + (int)threadIdx.x) >> 6;   // dst node
    int lane = threadIdx.x & 63;
    int sub = lane >> 3;          // edge slot
    int cg  = lane & 7;           // channel group
    int beg = rowptr[gw];
    int end = wofs[gw];
    float Z = *Zp;
    float invZ = (Z > 0.0f) ? 1.0f / Z : 0.0f;

    float acc[8];
#pragma unroll
    for (int k = 0; k < 8; ++k) acc[k] = 0.0f;

    for (int j0 = beg; j0 < end; j0 += 8) {
        int j = j0 + sub;
        bool valid = j < end;
        int jj = valid ? j : beg;
        float t = valid ? w32[jj] : 0.0f;
        int s = psrc[jj];
        bfvec8 v = *(const bfvec8*)(whb + (size_t)s * OUT_CH + cg * 8);
#pragma unroll
        for (int k = 0; k < 8; ++k) acc[k] += t * (float)v[k];
    }

#pragma unroll
    for (int mask = 8; mask <= 32; mask <<= 1) {
#pragma unroll
        for (int k = 0; k < 8; ++k) acc[k] += __shfl_xor(acc[k], mask);
    }

    if (sub == 0) {
        floatx4 o0, o1;
#pragma unroll
        for (int k = 0; k < 4; ++k) {
            float h = acc[k] * invZ;
            o0[k] = h > 0.0f ? h : expf(h) - 1.0f;
        }
#pragma unroll
        for (int k = 0; k < 4; ++k) {
            float h = acc[4 + k] * invZ;
            o1[k] = h > 0.0f ? h : expf(h) - 1.0f;
        }
        float* dst = out + (size_t)gw * OUT_CH + cg * 8;
        *(floatx4*)(dst)     = o0;
        *(floatx4*)(dst + 4) = o1;
    }
}

extern "C" void kernel_launch(void* const* d_in, const int* in_sizes, int n_in,
                              void* d_out, int out_size, void* d_ws, size_t ws_size,
                              hipStream_t stream) {
    const void* x  = d_in[0];
    const int* ei  = (const int*)d_in[1];
    const void* W  = d_in[2];
    const void* a  = d_in[3];
    float* out     = (float*)d_out;

    char* ws = (char*)d_ws;
    __bf16* whb  = (__bf16*)(ws + WS_WHB);
    float* w32   = (float*)(ws + WS_W32);
    unsigned short* psrc  = (unsigned short*)(ws + WS_PSRC);
    unsigned short* src16 = (unsigned short*)(ws + WS_SRC16);
    unsigned short* dst16 = (unsigned short*)(ws + WS_DST16);
    int* cnt     = (int*)(ws + WS_CNT);
    int* rowptr  = (int*)(ws + WS_ROWP);
    int* wofs    = (int*)(ws + WS_WOFS);
    __bf16* Wth  = (__bf16*)(ws + WS_WTH);
    __bf16* Wtl  = (__bf16*)(ws + WS_WTL);
    float* esrc  = (float*)(ws + WS_ESRC);
    float* edst  = (float*)(ws + WS_EDST);
    float* bmax  = (float*)(ws + WS_BMAX);
    float* bsum  = (float*)(ws + WS_BSUM);
    int*   btot  = (int*)(ws + WS_BTOT);
    int*   bbase = (int*)(ws + WS_BBASE);
    float* M     = (float*)(ws + WS_M);
    float* Z     = (float*)(ws + WS_Z);
    int*   flags = (int*)(ws + WS_FLAGS);

    hipMemsetAsync(cnt, 0, N_NODES * sizeof(int), stream);

    k_flags <<<1,      256, 0, stream>>>(ei, (const unsigned*)x, flags);
    k_prep  <<<64,     256, 0, stream>>>(W, flags, Wth, Wtl);
    k_mm    <<<782,    256, 0, stream>>>(x, Wth, Wtl, a, flags, whb, esrc, edst);
    k_edge  <<<NBLK_E, 256, 0, stream>>>(ei, flags, esrc, edst, src16, dst16, cnt, bmax);
    k_scanA <<<NBLK_N, 256, 0, stream>>>(cnt, rowptr, btot);
    k_scanB <<<1,      256, 0, stream>>>(btot, bbase, bmax, M);
    k_scanC <<<NBLK_N, 256, 0, stream>>>(rowptr, wofs, bbase);
    k_exp   <<<NBLK_E, 256, 0, stream>>>(M, esrc, edst, src16, dst16, wofs, w32, psrc, bsum);
    k_rsum  <<<1,      256, 0, stream>>>(bsum, Z);
    k_gather<<<N_NODES / 4, 256, 0, stream>>>(rowptr, wofs, w32, psrc, whb, Z, out);
}

// Round 10
// 190.826 us; speedup vs baseline: 1.7425x; 1.1137x over previous
//
#include <hip/hip_runtime.h>
#include <hip/hip_bf16.h>

#define N_NODES 50000
#define N_EDGES 800000
#define IN_CH 256
#define OUT_CH 64
#define NEG_BIG -9e15f
#define NBLK_E 3125   // N_EDGES / 256
#define NBLK_N 196    // ceil(50000/256)

typedef __bf16 bfvec8 __attribute__((ext_vector_type(8)));
typedef float floatx4 __attribute__((ext_vector_type(4)));

// ---- ws layout (bytes), total ~15.5 MB ----
#define WS_WHB   0          // bf16 [50000][64]   6,400,000
#define WS_W32   6400000    // fp32 [800000]      3,200,000  sorted exp weights
#define WS_PSRC  9600000    // u16  [800000]      1,600,000  sorted src
#define WS_SRC16 11200000   // u16  [800000]      1,600,000
#define WS_DST16 12800000   // u16  [800000]      1,600,000
#define WS_CNT   14400000   // int  [50000]
#define WS_ROWP  14600000   // int  [50000]
#define WS_WOFS  14800000   // int  [50000]
#define WS_WTH   15000000   // bf16 [64][256]        32,768
#define WS_WTL   15040000   // bf16 [64][256]        32,768
#define WS_ESRC  15080000   // fp32 [50000]
#define WS_EDST  15280000   // fp32 [50000]
#define WS_BMAX  15480000   // fp32 [3125]
#define WS_BSUM  15496000   // fp32 [3125]
#define WS_BTOT  15512000   // int  [196]
#define WS_BBASE 15513000   // int  [196]
#define WS_M     15514000
#define WS_Z     15514004
#define WS_FLAGS 15514008   // int[2]: {edge_is_i64, float_is_f32}

// ---------- dtype-flexible helpers ----------
__device__ __forceinline__ float loadf(const void* p, size_t i, int isf32) {
    return isf32 ? ((const float*)p)[i]
                 : __bfloat162float(((const __hip_bfloat16*)p)[i]);
}
__device__ __forceinline__ void load_edge(const int* __restrict__ ei, int i, int f64,
                                          int& s, int& d) {
    if (f64) {
        int2 ps = ((const int2*)ei)[i];
        int2 pd = ((const int2*)ei)[N_EDGES + i];
        s = ps.x; d = pd.x;
    } else {
        s = ei[i]; d = ei[N_EDGES + i];
    }
    s = min(max(s, 0), N_NODES - 1);
    d = min(max(d, 0), N_NODES - 1);
}

// ---------- K0: detect edge int64 and float fp32 ----------
__global__ __launch_bounds__(256) void k_flags(const int* __restrict__ ei,
                                               const unsigned* __restrict__ xw,
                                               int* __restrict__ flags) {
    int t = threadIdx.x;
    int v = 0;
    for (int i = t; i < 2048; i += 256) v |= ei[2 * i + 1];
    unsigned lo = xw[t] & 0xFFFFu;
    unsigned e8 = (lo >> 7) & 0xFFu;
    int hit = (e8 >= 96u && e8 <= 144u) ? 1 : 0;
#pragma unroll
    for (int off = 32; off > 0; off >>= 1) {
        v |= __shfl_down(v, off);
        hit += __shfl_down(hit, off);
    }
    __shared__ int sv[4], sh[4];
    if ((t & 63) == 0) { sv[t >> 6] = v; sh[t >> 6] = hit; }
    __syncthreads();
    if (t == 0) {
        flags[0] = ((sv[0] | sv[1] | sv[2] | sv[3]) == 0) ? 1 : 0;
        flags[1] = ((sh[0] + sh[1] + sh[2] + sh[3]) < 192) ? 1 : 0;
    }
}

// ---------- K1: Wt hi/lo split-transpose ----------
__global__ __launch_bounds__(256) void k_prep(const void* __restrict__ Wv,
                                              const int* __restrict__ flags,
                                              __bf16* __restrict__ Wth,
                                              __bf16* __restrict__ Wtl) {
    int isf = flags[1];
    int t = blockIdx.x * 256 + threadIdx.x;   // 0..16383
    int c = t >> 8, k = t & 255;
    float w = loadf(Wv, (size_t)k * OUT_CH + c, isf);
    __bf16 h = (__bf16)w;
    Wth[t] = h;
    Wtl[t] = (__bf16)(w - (float)h);
}

// ---------- K2: wh = x @ W via split-bf16 MFMA; Wt staged in LDS ----------
// LDS layout: lW[hi/lo][row][k] with 16B chunks xor-swizzled: chunk' = chunk ^ (row&31)
// -> ds_read_b128 in K-loop is bank-conflict-free (8 LDS cycles, optimal).
__global__ __launch_bounds__(256, 2) void k_mm(const void* __restrict__ xv,
                                               const __bf16* __restrict__ Wth,
                                               const __bf16* __restrict__ Wtl,
                                               const void* __restrict__ av,
                                               const int* __restrict__ flags,
                                               __bf16* __restrict__ whb,
                                               float* __restrict__ esrc,
                                               float* __restrict__ edst) {
    __shared__ __bf16 lW[2][64 * 256];        // 64 KB
    int tid = threadIdx.x;
    int isf = flags[1];
    int gw = (blockIdx.x * 256 + tid) >> 6;
    int lane = tid & 63;
    int m = lane & 15, quad = lane >> 4;
    int nb = gw * 16;
    bool active = gw < N_NODES / 16;          // wave-uniform

    // ---- hoisted x loads: 16 (fp32) / 8 (bf16) VMEM ops in flight ----
    floatx4 x0[8], x1[8];
    bfvec8 xa[8];
    if (active) {
        if (isf) {
            const float* xr = (const float*)xv + (size_t)(nb + m) * IN_CH + quad * 8;
#pragma unroll
            for (int s = 0; s < 8; ++s) {
                x0[s] = *(const floatx4*)(xr + s * 32);
                x1[s] = *(const floatx4*)(xr + s * 32 + 4);
            }
        } else {
            const __bf16* xr = (const __bf16*)xv + (size_t)(nb + m) * IN_CH + quad * 8;
#pragma unroll
            for (int s = 0; s < 8; ++s) xa[s] = *(const bfvec8*)(xr + s * 32);
        }
    }

    // ---- stage Wth/Wtl -> LDS (coalesced global, swizzled LDS chunks) ----
#pragma unroll
    for (int i = 0; i < 8; ++i) {
        int f = i * 256 + tid;                // chunk id 0..2047
        int r = f >> 5, c = f & 31;
        int cs = c ^ (r & 31);
        *(bfvec8*)(&lW[0][r * 256 + cs * 8]) = *(const bfvec8*)(Wth + r * 256 + c * 8);
        *(bfvec8*)(&lW[1][r * 256 + cs * 8]) = *(const bfvec8*)(Wtl + r * 256 + c * 8);
    }
    __syncthreads();

    if (!active) return;

    floatx4 acc[4];
#pragma unroll
    for (int ct = 0; ct < 4; ++ct) acc[ct] = (floatx4){0.f, 0.f, 0.f, 0.f};

    if (isf) {
#pragma unroll
        for (int s = 0; s < 8; ++s) {
            float v[8];
            *(floatx4*)(v)     = x0[s];
            *(floatx4*)(v + 4) = x1[s];
            bfvec8 ahi, alo;
#pragma unroll
            for (int j = 0; j < 8; ++j) {
                __bf16 h = (__bf16)v[j];
                ahi[j] = h;
                alo[j] = (__bf16)(v[j] - (float)h);
            }
#pragma unroll
            for (int ct = 0; ct < 4; ++ct) {
                int row = ct * 16 + m;
                int cs = ((s * 4 + quad) ^ (row & 31)) * 8;
                bfvec8 bhi = *(const bfvec8*)(&lW[0][row * 256 + cs]);
                bfvec8 blo = *(const bfvec8*)(&lW[1][row * 256 + cs]);
                acc[ct] = __builtin_amdgcn_mfma_f32_16x16x32_bf16(ahi, blo, acc[ct], 0, 0, 0);
                acc[ct] = __builtin_amdgcn_mfma_f32_16x16x32_bf16(alo, bhi, acc[ct], 0, 0, 0);
                acc[ct] = __builtin_amdgcn_mfma_f32_16x16x32_bf16(ahi, bhi, acc[ct], 0, 0, 0);
            }
        }
    } else {
#pragma unroll
        for (int s = 0; s < 8; ++s) {
#pragma unroll
            for (int ct = 0; ct < 4; ++ct) {
                int row = ct * 16 + m;
                int cs = ((s * 4 + quad) ^ (row & 31)) * 8;
                bfvec8 bhi = *(const bfvec8*)(&lW[0][row * 256 + cs]);
                bfvec8 blo = *(const bfvec8*)(&lW[1][row * 256 + cs]);
                acc[ct] = __builtin_amdgcn_mfma_f32_16x16x32_bf16(xa[s], blo, acc[ct], 0, 0, 0);
                acc[ct] = __builtin_amdgcn_mfma_f32_16x16x32_bf16(xa[s], bhi, acc[ct], 0, 0, 0);
            }
        }
    }

    float a1[4], a2[4];
#pragma unroll
    for (int ct = 0; ct < 4; ++ct) {
        a1[ct] = loadf(av, ct * 16 + m, isf);
        a2[ct] = loadf(av, OUT_CH + ct * 16 + m, isf);
    }
#pragma unroll
    for (int r = 0; r < 4; ++r) {
        int node = nb + quad * 4 + r;
        float s1 = 0.f, s2 = 0.f;
#pragma unroll
        for (int ct = 0; ct < 4; ++ct) {
            float vv = acc[ct][r];
            whb[(size_t)node * OUT_CH + ct * 16 + m] = (__bf16)vv;
            s1 += vv * a1[ct];
            s2 += vv * a2[ct];
        }
#pragma unroll
        for (int off = 1; off < 16; off <<= 1) {
            s1 += __shfl_xor(s1, off);
            s2 += __shfl_xor(s2, off);
        }
        if (m == 0) { esrc[node] = s1; edst[node] = s2; }
    }
}

// ---------- K3: u16 idx + filtered histogram + block max ----------
__global__ __launch_bounds__(256) void k_edge(const int* __restrict__ ei,
                                              const int* __restrict__ flags,
                                              const float* __restrict__ esrc,
                                              const float* __restrict__ edst,
                                              unsigned short* __restrict__ src16,
                                              unsigned short* __restrict__ dst16,
                                              int* __restrict__ cnt,
                                              float* __restrict__ bmax) {
    int f64 = flags[0];
    int i = blockIdx.x * 256 + threadIdx.x;
    int s, d;
    load_edge(ei, i, f64, s, d);
    src16[i] = (unsigned short)s;
    dst16[i] = (unsigned short)d;
    float v = esrc[s] + edst[d];
    float ev = v > 0.0f ? v : NEG_BIG;
    if (v > 0.0f) atomicAdd(&cnt[d], 1);
    float mx = ev;
#pragma unroll
    for (int off = 32; off > 0; off >>= 1) mx = fmaxf(mx, __shfl_down(mx, off));
    __shared__ float sm[4];
    if ((threadIdx.x & 63) == 0) sm[threadIdx.x >> 6] = mx;
    __syncthreads();
    if (threadIdx.x == 0)
        bmax[blockIdx.x] = fmaxf(fmaxf(sm[0], sm[1]), fmaxf(sm[2], sm[3]));
}

// ---------- K4a: per-block scan of cnt (196 blocks) ----------
__global__ __launch_bounds__(256) void k_scanA(const int* __restrict__ cnt,
                                               int* __restrict__ rowptr,
                                               int* __restrict__ btot) {
    int t = threadIdx.x, lane = t & 63, wid = t >> 6;
    int idx = blockIdx.x * 256 + t;
    int v = (idx < N_NODES) ? cnt[idx] : 0;
    int incl = v;
#pragma unroll
    for (int off = 1; off < 64; off <<= 1) {
        int u = __shfl_up(incl, off);
        if (lane >= off) incl += u;
    }
    __shared__ int wsum[4];
    if (lane == 63) wsum[wid] = incl;
    __syncthreads();
    int wbase = 0;
#pragma unroll
    for (int w = 0; w < 4; ++w) if (w < wid) wbase += wsum[w];
    if (idx < N_NODES) rowptr[idx] = wbase + incl - v;
    if (t == 255) btot[blockIdx.x] = wbase + incl;
}

// ---------- K4b: scan 196 block totals + bmax -> M ----------
__global__ __launch_bounds__(256) void k_scanB(const int* __restrict__ btot,
                                               int* __restrict__ bbase,
                                               const float* __restrict__ bmax,
                                               float* __restrict__ M) {
    int t = threadIdx.x, lane = t & 63, wid = t >> 6;
    float mx = NEG_BIG;
    for (int i = t; i < NBLK_E; i += 256) mx = fmaxf(mx, bmax[i]);
#pragma unroll
    for (int off = 32; off > 0; off >>= 1) mx = fmaxf(mx, __shfl_down(mx, off));
    __shared__ float smax[4];
    if (lane == 0) smax[wid] = mx;

    int v = (t < NBLK_N) ? btot[t] : 0;
    int incl = v;
#pragma unroll
    for (int off = 1; off < 64; off <<= 1) {
        int u = __shfl_up(incl, off);
        if (lane >= off) incl += u;
    }
    __shared__ int wsum[4];
    if (lane == 63) wsum[wid] = incl;
    __syncthreads();
    int wbase = 0;
#pragma unroll
    for (int w = 0; w < 4; ++w) if (w < wid) wbase += wsum[w];
    if (t < NBLK_N) bbase[t] = wbase + incl - v;
    if (t == 0) *M = fmaxf(fmaxf(smax[0], smax[1]), fmaxf(smax[2], smax[3]));
}

// ---------- K4c: add block bases ----------
__global__ __launch_bounds__(256) void k_scanC(int* __restrict__ rowptr,
                                               int* __restrict__ wofs,
                                               const int* __restrict__ bbase) {
    int idx = blockIdx.x * 256 + threadIdx.x;
    if (idx < N_NODES) {
        int r = rowptr[idx] + bbase[blockIdx.x];
        rowptr[idx] = r;
        wofs[idx] = r;
    }
}

// ---------- K5: exp (recomputed scores) + block sum + CSR placement ----------
__global__ __launch_bounds__(256) void k_exp(const float* __restrict__ Mp,
                                             const float* __restrict__ esrc,
                                             const float* __restrict__ edst,
                                             const unsigned short* __restrict__ src16,
                                             const unsigned short* __restrict__ dst16,
                                             int* __restrict__ wofs,
                                             float* __restrict__ w32,
                                             unsigned short* __restrict__ psrc,
                                             float* __restrict__ bsum) {
    float M = *Mp;
    int i = blockIdx.x * 256 + threadIdx.x;
    int s = src16[i], d = dst16[i];
    float v = esrc[s] + edst[d];
    float ev = v > 0.0f ? v : NEG_BIG;
    float t = expf(ev - M);          // masked edges: exp(-9e15-M) == 0
    if (v > 0.0f) {
        int pos = atomicAdd(&wofs[d], 1);
        w32[pos] = t;
        psrc[pos] = (unsigned short)s;
    }
#pragma unroll
    for (int off = 32; off > 0; off >>= 1) t += __shfl_down(t, off);
    __shared__ float sm[4];
    if ((threadIdx.x & 63) == 0) sm[threadIdx.x >> 6] = t;
    __syncthreads();
    if (threadIdx.x == 0) bsum[blockIdx.x] = sm[0] + sm[1] + sm[2] + sm[3];
}

// ---------- K6: reduce block sums -> Z ----------
__global__ __launch_bounds__(256) void k_rsum(const float* __restrict__ bsum,
                                              float* __restrict__ Z) {
    float s = 0.0f;
    for (int i = threadIdx.x; i < NBLK_E; i += 256) s += bsum[i];
#pragma unroll
    for (int off = 32; off > 0; off >>= 1) s += __shfl_down(s, off);
    __shared__ float sm[4];
    if ((threadIdx.x & 63) == 0) sm[threadIdx.x >> 6] = s;
    __syncthreads();
    if (threadIdx.x == 0) *Z = sm[0] + sm[1] + sm[2] + sm[3];
}

// ---------- K7: CSR gather, wave per dst node, 8 edges in flight ----------
__global__ __launch_bounds__(256) void k_gather(const int* __restrict__ rowptr,
                                                const int* __restrict__ wofs,
                                                const float* __restrict__ w32,
                                                const unsigned short* __restrict__ psrc,
                                                const __bf16* __restrict__ whb,
                                                const float* __restrict__ Zp,
                                                float* __restrict__ out) {
    int gw = (blockIdx.x * 256 + (int)threadIdx.x) >> 6;   // dst node
    int lane = threadIdx.x & 63;
    int sub = lane >> 3;          // edge slot
    int cg  = lane & 7;           // channel group
    int beg = rowptr[gw];
    int end = wofs[gw];
    float Z = *Zp;
    float invZ = (Z > 0.0f) ? 1.0f / Z : 0.0f;

    float acc[8];
#pragma unroll
    for (int k = 0; k < 8; ++k) acc[k] = 0.0f;

    for (int j0 = beg; j0 < end; j0 += 8) {
        int j = j0 + sub;
        bool valid = j < end;
        int jj = valid ? j : beg;
        float t = valid ? w32[jj] : 0.0f;
        int s = psrc[jj];
        bfvec8 v = *(const bfvec8*)(whb + (size_t)s * OUT_CH + cg * 8);
#pragma unroll
        for (int k = 0; k < 8; ++k) acc[k] += t * (float)v[k];
    }

#pragma unroll
    for (int mask = 8; mask <= 32; mask <<= 1) {
#pragma unroll
        for (int k = 0; k < 8; ++k) acc[k] += __shfl_xor(acc[k], mask);
    }

    if (sub == 0) {
        floatx4 o0, o1;
#pragma unroll
        for (int k = 0; k < 4; ++k) {
            float h = acc[k] * invZ;
            o0[k] = h > 0.0f ? h : expf(h) - 1.0f;
        }
#pragma unroll
        for (int k = 0; k < 4; ++k) {
            float h = acc[4 + k] * invZ;
            o1[k] = h > 0.0f ? h : expf(h) - 1.0f;
        }
        float* dst = out + (size_t)gw * OUT_CH + cg * 8;
        *(floatx4*)(dst)     = o0;
        *(floatx4*)(dst + 4) = o1;
    }
}

extern "C" void kernel_launch(void* const* d_in, const int* in_sizes, int n_in,
                              void* d_out, int out_size, void* d_ws, size_t ws_size,
                              hipStream_t stream) {
    const void* x  = d_in[0];
    const int* ei  = (const int*)d_in[1];
    const void* W  = d_in[2];
    const void* a  = d_in[3];
    float* out     = (float*)d_out;

    char* ws = (char*)d_ws;
    __bf16* whb  = (__bf16*)(ws + WS_WHB);
    float* w32   = (float*)(ws + WS_W32);
    unsigned short* psrc  = (unsigned short*)(ws + WS_PSRC);
    unsigned short* src16 = (unsigned short*)(ws + WS_SRC16);
    unsigned short* dst16 = (unsigned short*)(ws + WS_DST16);
    int* cnt     = (int*)(ws + WS_CNT);
    int* rowptr  = (int*)(ws + WS_ROWP);
    int* wofs    = (int*)(ws + WS_WOFS);
    __bf16* Wth  = (__bf16*)(ws + WS_WTH);
    __bf16* Wtl  = (__bf16*)(ws + WS_WTL);
    float* esrc  = (float*)(ws + WS_ESRC);
    float* edst  = (float*)(ws + WS_EDST);
    float* bmax  = (float*)(ws + WS_BMAX);
    float* bsum  = (float*)(ws + WS_BSUM);
    int*   btot  = (int*)(ws + WS_BTOT);
    int*   bbase = (int*)(ws + WS_BBASE);
    float* M     = (float*)(ws + WS_M);
    float* Z     = (float*)(ws + WS_Z);
    int*   flags = (int*)(ws + WS_FLAGS);

    hipMemsetAsync(cnt, 0, N_NODES * sizeof(int), stream);

    k_flags <<<1,      256, 0, stream>>>(ei, (const unsigned*)x, flags);
    k_prep  <<<64,     256, 0, stream>>>(W, flags, Wth, Wtl);
    k_mm    <<<782,    256, 0, stream>>>(x, Wth, Wtl, a, flags, whb, esrc, edst);
    k_edge  <<<NBLK_E, 256, 0, stream>>>(ei, flags, esrc, edst, src16, dst16, cnt, bmax);
    k_scanA <<<NBLK_N, 256, 0, stream>>>(cnt, rowptr, btot);
    k_scanB <<<1,      256, 0, stream>>>(btot, bbase, bmax, M);
    k_scanC <<<NBLK_N, 256, 0, stream>>>(rowptr, wofs, bbase);
    k_exp   <<<NBLK_E, 256, 0, stream>>>(M, esrc, edst, src16, dst16, wofs, w32, psrc, bsum);
    k_rsum  <<<1,      256, 0, stream>>>(bsum, Z);
    k_gather<<<N_NODES / 4, 256, 0, stream>>>(rowptr, wofs, w32, psrc, whb, Z, out);
}